// Round 1
// baseline (379.069 us; speedup 1.0000x reference)
//
#include <hip/hip_runtime.h>

#define NB 4096
#define F0 32
#define F1 32
#define NE 32
#define NI 496            // 32*31/2
#define BN_EPS 1e-5f

__device__ __forceinline__ void pair_rc(int i, int& r, int& c) {
    int rem = i, rr = 0;
    while (rem >= F1 - 1 - rr) { rem -= F1 - 1 - rr; ++rr; }
    r = rr; c = rr + 1 + rem;
}

// ---------------- Kernel 1: BN stats -> scale/shift per interaction ----------
__global__ __launch_bounds__(256) void stats_kernel(
        const float* __restrict__ xi, const float* __restrict__ xj,
        const float* __restrict__ gamma, const float* __restrict__ beta,
        float* __restrict__ scale, float* __restrict__ shift) {
    const int i = blockIdx.x;
    int r, c; pair_rc(i, r, c);
    const int t  = threadIdx.x;
    const int e4 = t & 7;        // which float4 of the 32-wide row
    const int bs = t >> 3;       // 32 batches in flight per pass

    const float4* xi4 = (const float4*)xi;
    const float4* xj4 = (const float4*)xj;

    float4 s1 = {0.f,0.f,0.f,0.f};
    float4 s2 = {0.f,0.f,0.f,0.f};
    for (int b = bs; b < NB; b += 32) {
        float4 a = xi4[(b*F0 + r)*8 + e4];
        float4 q = xj4[(b*F1 + c)*8 + e4];
        float x0 = a.x*q.x, x1 = a.y*q.y, x2 = a.z*q.z, x3 = a.w*q.w;
        s1.x += x0; s1.y += x1; s1.z += x2; s1.w += x3;
        s2.x += x0*x0; s2.y += x1*x1; s2.z += x2*x2; s2.w += x3*x3;
    }
    float p1 = (s1.x + s1.y) + (s1.z + s1.w);
    float p2 = (s2.x + s2.y) + (s2.z + s2.w);
    for (int off = 32; off; off >>= 1) {
        p1 += __shfl_down(p1, off);
        p2 += __shfl_down(p2, off);
    }
    __shared__ float r1[4], r2[4];
    const int wv = t >> 6;
    if ((t & 63) == 0) { r1[wv] = p1; r2[wv] = p2; }
    __syncthreads();
    if (t == 0) {
        float S1 = (r1[0] + r1[1]) + (r1[2] + r1[3]);
        float S2 = (r2[0] + r2[1]) + (r2[2] + r2[3]);
        const float invN = 1.0f / (float)(NB * NE);
        float mean = S1 * invN;
        float var  = S2 * invN - mean * mean;
        float sc   = gamma[i] / sqrtf(var + BN_EPS);
        scale[i] = sc;
        shift[i] = beta[i] - mean * sc;
    }
}

// ---------------- Kernel 2: fused normalize * W -> attn -> softmax -> out ----
__global__ __launch_bounds__(256) void main_kernel(
        const float* __restrict__ xi, const float* __restrict__ xj,
        const float* __restrict__ W,
        const float* __restrict__ attn_w, const float* __restrict__ attn_b,
        const float* __restrict__ proj_w, const float* __restrict__ proj_b,
        const float* __restrict__ scale, const float* __restrict__ shift,
        float* __restrict__ out) {
    __shared__ float xi_l[F0 * 33];   // +1 pad breaks bank aliasing
    __shared__ float xj_l[F1 * 33];
    __shared__ float ss_l[NI * 2];    // interleaved scale, shift
    __shared__ float lg[NI];          // logits, then softmax scores
    __shared__ int   rc_l[NI];
    __shared__ float redm[4], reds[4];

    const int b = blockIdx.x;
    const int t = threadIdx.x;

    // ---- Phase A: stage xi/xj rows (1024 floats each) + scale/shift ----
    {
        const float4* x4 = (const float4*)(xi + (size_t)b * F0 * NE);
        const float4* y4 = (const float4*)(xj + (size_t)b * F1 * NE);
        float4 v = x4[t];
        int r = t >> 3, e0 = (t & 7) * 4;
        xi_l[r*33 + e0 + 0] = v.x; xi_l[r*33 + e0 + 1] = v.y;
        xi_l[r*33 + e0 + 2] = v.z; xi_l[r*33 + e0 + 3] = v.w;
        v = y4[t];
        xj_l[r*33 + e0 + 0] = v.x; xj_l[r*33 + e0 + 1] = v.y;
        xj_l[r*33 + e0 + 2] = v.z; xj_l[r*33 + e0 + 3] = v.w;
        for (int s = t; s < NI; s += 256) {
            ss_l[2*s]   = scale[s];
            ss_l[2*s+1] = shift[s];
        }
    }
    __syncthreads();

    const float4* W4  = (const float4*)W;
    const float4* aw4 = (const float4*)attn_w;
    const float4* ab4 = (const float4*)attn_b;
    const float4* pw4 = (const float4*)proj_w;
    const float  pb   = proj_b[0];

    // ---- Phase B: per-interaction o[], 32x32 matvec, ReLU, proj -> logit ----
    for (int round = 0; round < 2; ++round) {
        const int i = t + round * 256;
        if (i < NI) {
            int r, c; pair_rc(i, r, c);
            rc_l[i] = (r << 5) | c;
            const float sc = ss_l[2*i], sh = ss_l[2*i+1];
            float o[NE];
            #pragma unroll
            for (int j = 0; j < 8; ++j) {
                float4 w = W4[i*8 + j];
                int e0 = j * 4;
                o[e0+0] = w.x * (sc * xi_l[r*33+e0+0] * xj_l[c*33+e0+0] + sh);
                o[e0+1] = w.y * (sc * xi_l[r*33+e0+1] * xj_l[c*33+e0+1] + sh);
                o[e0+2] = w.z * (sc * xi_l[r*33+e0+2] * xj_l[c*33+e0+2] + sh);
                o[e0+3] = w.w * (sc * xi_l[r*33+e0+3] * xj_l[c*33+e0+3] + sh);
            }
            float logit = pb;
            #pragma unroll
            for (int a4 = 0; a4 < 8; ++a4) {
                float4 hb = ab4[a4];
                float h0 = hb.x, h1 = hb.y, h2 = hb.z, h3 = hb.w;
                #pragma unroll
                for (int e = 0; e < NE; ++e) {
                    float4 wr = aw4[e*8 + a4];   // uniform address -> scalar/L1 broadcast
                    h0 += o[e] * wr.x; h1 += o[e] * wr.y;
                    h2 += o[e] * wr.z; h3 += o[e] * wr.w;
                }
                float4 pw = pw4[a4];
                logit += fmaxf(h0, 0.f) * pw.x + fmaxf(h1, 0.f) * pw.y
                       + fmaxf(h2, 0.f) * pw.z + fmaxf(h3, 0.f) * pw.w;
            }
            lg[i] = logit;
        }
    }
    __syncthreads();

    // ---- softmax over the 496 interactions ----
    float m = -1e30f;
    for (int f = t; f < NI; f += 256) m = fmaxf(m, lg[f]);
    for (int off = 32; off; off >>= 1) m = fmaxf(m, __shfl_xor(m, off));
    const int wv = t >> 6;
    if ((t & 63) == 0) redm[wv] = m;
    __syncthreads();
    m = fmaxf(fmaxf(redm[0], redm[1]), fmaxf(redm[2], redm[3]));

    float s = 0.f;
    for (int f = t; f < NI; f += 256) s += expf(lg[f] - m);
    for (int off = 32; off; off >>= 1) s += __shfl_xor(s, off);
    if ((t & 63) == 0) reds[wv] = s;
    __syncthreads();
    const float inv = 1.0f / ((reds[0] + reds[1]) + (reds[2] + reds[3]));

    for (int f = t; f < NI; f += 256) lg[f] = expf(lg[f] - m) * inv;
    __syncthreads();

    // ---- Phase C: recompute o and write scores * o, coalesced float4 ----
    float4* op4 = (float4*)(out + (size_t)b * NI * NE);
    for (int f4 = t; f4 < NI * 8; f4 += 256) {
        const int i  = f4 >> 3;
        const int e0 = (f4 & 7) * 4;
        const int rc = rc_l[i];
        const int r  = rc >> 5, c = rc & 31;
        const float sc = ss_l[2*i], sh = ss_l[2*i+1];
        const float score = lg[i];
        float4 w = W4[f4];
        float4 res;
        res.x = score * (w.x * (sc * xi_l[r*33+e0+0] * xj_l[c*33+e0+0] + sh));
        res.y = score * (w.y * (sc * xi_l[r*33+e0+1] * xj_l[c*33+e0+1] + sh));
        res.z = score * (w.z * (sc * xi_l[r*33+e0+2] * xj_l[c*33+e0+2] + sh));
        res.w = score * (w.w * (sc * xi_l[r*33+e0+3] * xj_l[c*33+e0+3] + sh));
        op4[f4] = res;
    }
}

extern "C" void kernel_launch(void* const* d_in, const int* in_sizes, int n_in,
                              void* d_out, int out_size, void* d_ws, size_t ws_size,
                              hipStream_t stream) {
    const float* xi     = (const float*)d_in[0];
    const float* xj     = (const float*)d_in[1];
    const float* W      = (const float*)d_in[2];
    const float* gamma  = (const float*)d_in[3];
    const float* beta   = (const float*)d_in[4];
    const float* attn_w = (const float*)d_in[5];
    const float* attn_b = (const float*)d_in[6];
    const float* proj_w = (const float*)d_in[7];
    const float* proj_b = (const float*)d_in[8];
    float* out = (float*)d_out;

    float* scale = (float*)d_ws;
    float* shift = scale + NI;

    stats_kernel<<<NI, 256, 0, stream>>>(xi, xj, gamma, beta, scale, shift);
    main_kernel<<<NB, 256, 0, stream>>>(xi, xj, W, attn_w, attn_b,
                                        proj_w, proj_b, scale, shift, out);
}

// Round 3
// 144.754 us; speedup vs baseline: 2.6187x; 2.6187x over previous
//
#include <hip/hip_runtime.h>

#define NB 4096
#define F0 32
#define F1 32
#define NE 32
#define NI 496            // 32*31/2
#define BN_EPS 1e-5f
#define XPAD 36           // row stride (floats) for xi/xj LDS tiles

typedef float f32x4_t __attribute__((ext_vector_type(4)));

__device__ __forceinline__ void pair_rc_loop(int i, int& r, int& c) {
    int rem = i, rr = 0;
    while (rem >= F1 - 1 - rr) { rem -= F1 - 1 - rr; ++rr; }
    r = rr; c = rr + 1 + rem;
}

// closed-form pair index with integer fixup: offset(r) = r*(63-r)/2
__device__ __forceinline__ void pair_rc_fast(int i, int& r, int& c) {
    int rr = (int)((63.0f - sqrtf(3969.0f - 8.0f * (float)i)) * 0.5f);
    int off = rr * (63 - rr) / 2;
    if (off > i) { --rr; off = rr * (63 - rr) / 2; }
    else {
        int off2 = (rr + 1) * (62 - rr) / 2;
        if (off2 <= i) { rr = rr + 1; off = off2; }
    }
    r = rr; c = rr + 1 + (i - off);
}

// ---------------- Kernel 1: BN stats -> scale/shift per interaction ----------
__global__ __launch_bounds__(256) void stats_kernel(
        const float* __restrict__ xi, const float* __restrict__ xj,
        const float* __restrict__ gamma, const float* __restrict__ beta,
        float* __restrict__ scale, float* __restrict__ shift) {
    const int i = blockIdx.x;
    int r, c; pair_rc_loop(i, r, c);
    const int t  = threadIdx.x;
    const int e4 = t & 7;
    const int bs = t >> 3;

    const float4* xi4 = (const float4*)xi;
    const float4* xj4 = (const float4*)xj;

    float4 s1 = {0.f,0.f,0.f,0.f};
    float4 s2 = {0.f,0.f,0.f,0.f};
    for (int b = bs; b < NB; b += 32) {
        float4 a = xi4[(b*F0 + r)*8 + e4];
        float4 q = xj4[(b*F1 + c)*8 + e4];
        float x0 = a.x*q.x, x1 = a.y*q.y, x2 = a.z*q.z, x3 = a.w*q.w;
        s1.x += x0; s1.y += x1; s1.z += x2; s1.w += x3;
        s2.x += x0*x0; s2.y += x1*x1; s2.z += x2*x2; s2.w += x3*x3;
    }
    float p1 = (s1.x + s1.y) + (s1.z + s1.w);
    float p2 = (s2.x + s2.y) + (s2.z + s2.w);
    for (int off = 32; off; off >>= 1) {
        p1 += __shfl_down(p1, off);
        p2 += __shfl_down(p2, off);
    }
    __shared__ float r1[4], r2[4];
    const int wv = t >> 6;
    if ((t & 63) == 0) { r1[wv] = p1; r2[wv] = p2; }
    __syncthreads();
    if (t == 0) {
        float S1 = (r1[0] + r1[1]) + (r1[2] + r1[3]);
        float S2 = (r2[0] + r2[1]) + (r2[2] + r2[3]);
        const float invN = 1.0f / (float)(NB * NE);
        float mean = S1 * invN;
        float var  = S2 * invN - mean * mean;
        float sc   = gamma[i] / sqrtf(var + BN_EPS);
        scale[i] = sc;
        shift[i] = beta[i] - mean * sc;
    }
}

// ---------------- Kernel 2: fused normalize * W -> attn -> softmax -> out ----
__global__ __launch_bounds__(256) void main_kernel(
        const float* __restrict__ xi, const float* __restrict__ xj,
        const float* __restrict__ W,
        const float* __restrict__ attn_w, const float* __restrict__ attn_b,
        const float* __restrict__ proj_w, const float* __restrict__ proj_b,
        const float* __restrict__ scale, const float* __restrict__ shift,
        float* __restrict__ out) {
    __shared__ __attribute__((aligned(16))) float xi_l[F0 * XPAD];
    __shared__ __attribute__((aligned(16))) float xj_l[F1 * XPAD];
    __shared__ float ss_l[NI * 2];    // interleaved scale, shift
    __shared__ float lg[NI];          // logits, then softmax scores
    __shared__ int   rc_l[NI];
    __shared__ float redm[4], reds[4];

    const int b = blockIdx.x;
    const int t = threadIdx.x;

    // ---- Phase A: stage xi/xj rows + scale/shift ----
    {
        const float4* x4 = (const float4*)(xi + (size_t)b * F0 * NE);
        const float4* y4 = (const float4*)(xj + (size_t)b * F1 * NE);
        const int r  = t >> 3;
        const int e0 = (t & 7) * 4;
        *(float4*)&xi_l[r * XPAD + e0] = x4[t];
        *(float4*)&xj_l[r * XPAD + e0] = y4[t];
        for (int s = t; s < NI; s += 256) {
            ss_l[2*s]   = scale[s];
            ss_l[2*s+1] = shift[s];
        }
    }
    __syncthreads();

    const float4* W4  = (const float4*)W;
    const float4* aw4 = (const float4*)attn_w;
    const float4* ab4 = (const float4*)attn_b;
    const float4* pw4 = (const float4*)proj_w;
    const float  pb   = proj_b[0];

    // ---- Phase B: single pass over e; o computed on the fly, 8 f4 accums ----
    #pragma unroll
    for (int round = 0; round < 2; ++round) {
        const int i = t + round * 256;
        if (i < NI) {
            int r, c; pair_rc_fast(i, r, c);
            rc_l[i] = (r << 5) | c;
            const float sc = ss_l[2*i], sh = ss_l[2*i+1];
            const float4* xir = (const float4*)&xi_l[r * XPAD];
            const float4* xjc = (const float4*)&xj_l[c * XPAD];

            float4 h[8];
            #pragma unroll
            for (int a4 = 0; a4 < 8; ++a4) h[a4] = ab4[a4];

            #pragma unroll
            for (int g = 0; g < 8; ++g) {
                const float4 av = xir[g];
                const float4 qv = xjc[g];
                const float4 wv = W4[i*8 + g];
                float og[4];
                og[0] = wv.x * (sc * av.x * qv.x + sh);
                og[1] = wv.y * (sc * av.y * qv.y + sh);
                og[2] = wv.z * (sc * av.z * qv.z + sh);
                og[3] = wv.w * (sc * av.w * qv.w + sh);
                #pragma unroll
                for (int k = 0; k < 4; ++k) {
                    const float s = og[k];
                    const int e = 4*g + k;
                    #pragma unroll
                    for (int a4 = 0; a4 < 8; ++a4) {
                        const float4 wr = aw4[e*8 + a4];   // uniform -> s_load
                        h[a4].x += s * wr.x;
                        h[a4].y += s * wr.y;
                        h[a4].z += s * wr.z;
                        h[a4].w += s * wr.w;
                    }
                }
            }

            float logit = pb;
            #pragma unroll
            for (int a4 = 0; a4 < 8; ++a4) {
                const float4 pw = pw4[a4];
                logit += fmaxf(h[a4].x, 0.f) * pw.x + fmaxf(h[a4].y, 0.f) * pw.y
                       + fmaxf(h[a4].z, 0.f) * pw.z + fmaxf(h[a4].w, 0.f) * pw.w;
            }
            lg[i] = logit;
        }
    }
    __syncthreads();

    // ---- softmax over the 496 interactions ----
    float m = -1e30f;
    for (int f = t; f < NI; f += 256) m = fmaxf(m, lg[f]);
    for (int off = 32; off; off >>= 1) m = fmaxf(m, __shfl_xor(m, off));
    const int wv = t >> 6;
    if ((t & 63) == 0) redm[wv] = m;
    __syncthreads();
    m = fmaxf(fmaxf(redm[0], redm[1]), fmaxf(redm[2], redm[3]));

    float s = 0.f;
    for (int f = t; f < NI; f += 256) s += expf(lg[f] - m);
    for (int off = 32; off; off >>= 1) s += __shfl_xor(s, off);
    if ((t & 63) == 0) reds[wv] = s;
    __syncthreads();
    const float inv = 1.0f / ((reds[0] + reds[1]) + (reds[2] + reds[3]));

    for (int f = t; f < NI; f += 256) lg[f] = expf(lg[f] - m) * inv;
    __syncthreads();

    // ---- Phase C: recompute o and write scores * o, coalesced nt float4 ----
    f32x4_t* op4 = (f32x4_t*)(out + (size_t)b * NI * NE);
    for (int f4 = t; f4 < NI * 8; f4 += 256) {
        const int i  = f4 >> 3;
        const int e0 = (f4 & 7) * 4;
        const int rc = rc_l[i];
        const int r  = rc >> 5, c = rc & 31;
        const float sc = ss_l[2*i], sh = ss_l[2*i+1];
        const float score = lg[i];
        const float4 w = W4[f4];
        f32x4_t res;
        res.x = score * (w.x * (sc * xi_l[r*XPAD+e0+0] * xj_l[c*XPAD+e0+0] + sh));
        res.y = score * (w.y * (sc * xi_l[r*XPAD+e0+1] * xj_l[c*XPAD+e0+1] + sh));
        res.z = score * (w.z * (sc * xi_l[r*XPAD+e0+2] * xj_l[c*XPAD+e0+2] + sh));
        res.w = score * (w.w * (sc * xi_l[r*XPAD+e0+3] * xj_l[c*XPAD+e0+3] + sh));
        __builtin_nontemporal_store(res, &op4[f4]);
    }
}

extern "C" void kernel_launch(void* const* d_in, const int* in_sizes, int n_in,
                              void* d_out, int out_size, void* d_ws, size_t ws_size,
                              hipStream_t stream) {
    const float* xi     = (const float*)d_in[0];
    const float* xj     = (const float*)d_in[1];
    const float* W      = (const float*)d_in[2];
    const float* gamma  = (const float*)d_in[3];
    const float* beta   = (const float*)d_in[4];
    const float* attn_w = (const float*)d_in[5];
    const float* attn_b = (const float*)d_in[6];
    const float* proj_w = (const float*)d_in[7];
    const float* proj_b = (const float*)d_in[8];
    float* out = (float*)d_out;

    float* scale = (float*)d_ws;
    float* shift = scale + NI;

    stats_kernel<<<NI, 256, 0, stream>>>(xi, xj, gamma, beta, scale, shift);
    main_kernel<<<NB, 256, 0, stream>>>(xi, xj, W, attn_w, attn_b,
                                        proj_w, proj_b, scale, shift, out);
}